// Round 1
// baseline (91.384 us; speedup 1.0000x reference)
//
#include <hip/hip_runtime.h>
#include <math.h>

// ---------------------------------------------------------------------------
// PGA(3,0,1)-style 4D Clifford algebra, metric (e0^2=0, e1^2=e2^2=e3^2=1).
// Blade order matches the reference BLADES list. All product tables derived
// at compile time from bitmasks (bit i of mask = e_i present in blade).
// ---------------------------------------------------------------------------
namespace ga {

// blade index -> bitmask
constexpr int MASK[16]        = {0,1,2,4,8,3,5,9,6,10,12,7,11,13,14,15};
// bitmask -> blade index
constexpr int IDX_OF_MASK[16] = {0,1,2,5,3,6,8,11,4,7,9,12,10,13,14,15};

constexpr int popcount4(int x) {
  return ((x >> 0) & 1) + ((x >> 1) & 1) + ((x >> 2) & 1) + ((x >> 3) & 1);
}

// Sign of sorting the concatenation (A ascending)(B ascending):
// (-1)^{# pairs (i in A, j in B) with i > j}
constexpr int reorder_sign(int a, int b) {
  int s = 0;
  for (int j = 0; j < 4; ++j)
    if ((b >> j) & 1) s += popcount4(a >> (j + 1));
  return (s & 1) ? -1 : 1;
}

struct Tab {
  float gp_s[16][16]; int gp_k[16][16];   // geometric product: 192 nonzeros
  float jn_s[16][16]; int jn_k[16][16];   // JOIN tensor:        81 nonzeros
};

constexpr Tab make_tab() {
  Tab t = {};
  for (int i = 0; i < 16; ++i) {
    for (int j = 0; j < 16; ++j) {
      const int a = MASK[i], b = MASK[j];
      // ---- geometric product: zero iff both contain e0 (e0^2 = 0);
      //      e1,e2,e3 square to +1 so metric contributes no sign.
      if (a & b & 1) {
        t.gp_s[i][j] = 0.0f; t.gp_k[i][j] = 0;
      } else {
        t.gp_s[i][j] = (float)reorder_sign(a, b);
        t.gp_k[i][j] = IDX_OF_MASK[a ^ b];
      }
      // ---- JOIN[i][j][k] = DINV[k,c] * WEDGE[da,db,c] * D[da,i] * D[db,j]
      // D is a signed permutation: D[idx(comp(i)), i] = reorder_sign(m_i, ~m_i)
      // DINV[k, idx(comp(k))] = reorder_sign(m_k, ~m_k)
      const int da = 15 ^ a, db = 15 ^ b;
      if (da & db) {
        t.jn_s[i][j] = 0.0f; t.jn_k[i][j] = 0;
      } else {
        const int si = reorder_sign(a, da);    // D[dual(i), i]
        const int sj = reorder_sign(b, db);    // D[dual(j), j]
        const int sw = reorder_sign(da, db);   // wedge of the duals
        const int cm = da | db;
        const int km = 15 ^ cm;                // output blade mask
        const int sk = reorder_sign(km, cm);   // DINV[k, c]
        t.jn_s[i][j] = (float)(si * sj * sw * sk);
        t.jn_k[i][j] = IDX_OF_MASK[km];
      }
    }
  }
  return t;
}

constexpr Tab T = make_tab();

} // namespace ga

// grade(d): [0,1,1,1,1,2,2,2,2,2,2,3,3,3,3,4]
// e0-multiplication partner pairs (d contains e0): (d, src) with sign +1:
// (1,0) (5,2) (6,3) (7,4) (11,8) (12,9) (13,10) (15,14); grade-4 (d=15)
// gets no v-term (GM[:4] truncation in the reference).
__device__ __forceinline__ void mv_linear(const float xin[16], const float w[5],
                                          const float v[4], float b, float y[16]) {
  y[0]  = w[0] * xin[0]  + b;
  y[1]  = w[1] * xin[1]  + v[1] * xin[0];
  y[2]  = w[1] * xin[2];
  y[3]  = w[1] * xin[3];
  y[4]  = w[1] * xin[4];
  y[5]  = w[2] * xin[5]  + v[2] * xin[2];
  y[6]  = w[2] * xin[6]  + v[2] * xin[3];
  y[7]  = w[2] * xin[7]  + v[2] * xin[4];
  y[8]  = w[2] * xin[8];
  y[9]  = w[2] * xin[9];
  y[10] = w[2] * xin[10];
  y[11] = w[3] * xin[11] + v[3] * xin[8];
  y[12] = w[3] * xin[12] + v[3] * xin[9];
  y[13] = w[3] * xin[13] + v[3] * xin[10];
  y[14] = w[3] * xin[14];
  y[15] = w[4] * xin[15];
}

__global__ void __launch_bounds__(256)
mv_ffn_kernel(const float* __restrict__ x,
              const float* __restrict__ w1, const float* __restrict__ v1, const float* __restrict__ b1,
              const float* __restrict__ wg, const float* __restrict__ vg, const float* __restrict__ bg,
              const float* __restrict__ wj, const float* __restrict__ vj, const float* __restrict__ bj,
              float* __restrict__ out, int ntok) {
  const int tid = blockIdx.x * blockDim.x + threadIdx.x;
  if (tid >= ntok) return;

  const float4* xp4 = reinterpret_cast<const float4*>(x) + (size_t)tid * 4;
  const float4 q0 = xp4[0], q1 = xp4[1], q2 = xp4[2], q3 = xp4[3];
  const float xv[16] = {q0.x, q0.y, q0.z, q0.w, q1.x, q1.y, q1.z, q1.w,
                        q2.x, q2.y, q2.z, q2.w, q3.x, q3.y, q3.z, q3.w};

  // xn = x / sqrt(sum over non-e0 blades {0,2,3,4,8,9,10,14} of x^2 + 1e-5)
  float n2 = 1e-5f;
  n2 += xv[0] * xv[0] + xv[2] * xv[2] + xv[3] * xv[3] + xv[4] * xv[4];
  n2 += xv[8] * xv[8] + xv[9] * xv[9] + xv[10] * xv[10] + xv[14] * xv[14];
  const float inv = 1.0f / sqrtf(n2);
  float xn[16];
#pragma unroll
  for (int i = 0; i < 16; ++i) xn[i] = xv[i] * inv;

  // tiny uniform weights (L1/L2 broadcast)
  const float W1[5] = {w1[0], w1[1], w1[2], w1[3], w1[4]};
  const float V1[4] = {v1[0], v1[1], v1[2], v1[3]};
  const float WG[5] = {wg[0], wg[1], wg[2], wg[3], wg[4]};
  const float VG[4] = {vg[0], vg[1], vg[2], vg[3]};
  const float WJ[5] = {wj[0], wj[1], wj[2], wj[3], wj[4]};
  const float VJ[4] = {vj[0], vj[1], vj[2], vj[3]};

  float xp_[16];
  mv_linear(xn, W1, V1, b1[0], xp_);

  // exact gelu on the scalar component, broadcast-multiplied
  const float s = xp_[0];
  const float g = 0.5f * s * (1.0f + erff(s * 0.70710678118654752440f));
  float xg[16];
#pragma unroll
  for (int i = 0; i < 16; ++i) xg[i] = g * xp_[i];

  // gp[k] = sum_ij xn[i]*xg[j]*GP[i][j][k]; jn likewise with JOIN.
  // Tables are constexpr; after full unroll the zero terms vanish and the
  // +-1 signs become fma sign modifiers (192 + 81 fmas).
  float gp[16], jn[16];
#pragma unroll
  for (int k = 0; k < 16; ++k) { gp[k] = 0.0f; jn[k] = 0.0f; }
#pragma unroll
  for (int i = 0; i < 16; ++i) {
#pragma unroll
    for (int j = 0; j < 16; ++j) {
      const float p = xn[i] * xg[j];
      const float sg = ga::T.gp_s[i][j];
      if (sg != 0.0f) gp[ga::T.gp_k[i][j]] += sg * p;
      const float sj = ga::T.jn_s[i][j];
      if (sj != 0.0f) jn[ga::T.jn_k[i][j]] += sj * p;
    }
  }
  const float pseudo = xn[15];
#pragma unroll
  for (int k = 0; k < 16; ++k) jn[k] *= pseudo;

  float y1[16], y2[16];
  mv_linear(gp, WG, VG, bg[0], y1);
  mv_linear(jn, WJ, VJ, bj[0], y2);

  float o[16];
#pragma unroll
  for (int k = 0; k < 16; ++k) o[k] = y1[k] + y2[k] + xv[k];

  float4* op4 = reinterpret_cast<float4*>(out) + (size_t)tid * 4;
  op4[0] = make_float4(o[0], o[1], o[2], o[3]);
  op4[1] = make_float4(o[4], o[5], o[6], o[7]);
  op4[2] = make_float4(o[8], o[9], o[10], o[11]);
  op4[3] = make_float4(o[12], o[13], o[14], o[15]);
}

extern "C" void kernel_launch(void* const* d_in, const int* in_sizes, int n_in,
                              void* d_out, int out_size, void* d_ws, size_t ws_size,
                              hipStream_t stream) {
  const float* x  = (const float*)d_in[0];
  const float* w1 = (const float*)d_in[1];
  const float* v1 = (const float*)d_in[2];
  const float* b1 = (const float*)d_in[3];
  const float* wg = (const float*)d_in[4];
  const float* vg = (const float*)d_in[5];
  const float* bg = (const float*)d_in[6];
  const float* wj = (const float*)d_in[7];
  const float* vj = (const float*)d_in[8];
  const float* bj = (const float*)d_in[9];
  float* out = (float*)d_out;

  const int ntok = in_sizes[0] / 16;  // 16*16384 = 262144 tokens
  const int block = 256;
  const int grid = (ntok + block - 1) / block;
  mv_ffn_kernel<<<grid, block, 0, stream>>>(x, w1, v1, b1, wg, vg, bg,
                                            wj, vj, bj, out, ntok);
}